// Round 1
// 196.712 us; speedup vs baseline: 1.0093x; 1.0093x over previous
//
#include <hip/hip_runtime.h>
#include <math.h>

// IdealScore: B=16, N=10000, D=3072, fp32.
//   arg[b][n] = (at/bt2)*dot(x_b, img_n) - ((1-sval)/(2*sval))*||img_n||^2
//   (x_sq dropped: softmax shift-invariant); w = softmax_n(arg);
//   out = (at*(w@imgs) - x)/bt2.  Near-one-hot softmax -> sparse pass 2.
//
// R11 = persistent k1: grid (192,4) = 768 blocks = exactly 3 blocks/CU
// (48 KB LDS), all co-resident. Each block stages its 48 KB x quarter-slice
// ONCE (was: 2500 blocks re-staging -> 120 MB L2 DMA + per-block barrier
// drain + churn bubbles), then loops barrier-free over 3-4 n-groups with
// the image prefetch rolling ACROSS group boundaries so the reduce-tail
// hides HBM latency. Images use nontemporal loads (each line read once).
// k2+k3 merged: selection lives in LDS, one launch fewer, no idx/wv
// global round-trip.
#define BB 16
#define NN 10000
#define DD 3072
#define DQ 768           // d-quarter
#define SEL_CUT 40.0f
#define CAP 1024         // selection capacity per batch row
#define PBX 192          // persistent blocks per quarter: 192*4 = 768 = 3/CU
#define NGRP 625         // n-groups of 16 rows: 625*16 = 10000

typedef const float __attribute__((address_space(1)))* gas_t;
typedef float __attribute__((address_space(3)))* las_t;

typedef float f4v __attribute__((ext_vector_type(4)));
__device__ __forceinline__ float4 ldnt4(const float* p) {
  f4v v = __builtin_nontemporal_load(reinterpret_cast<const f4v*>(p));
  return make_float4(v.x, v.y, v.z, v.w);
}

// verified reduce-scatter step (R6/R8/R9) on float2 accumulator array
#define RSTEP2(arr, mm, cc)                                             \
  {                                                                     \
    const bool up = (lane & (mm)) != 0;                                 \
    _Pragma("unroll")                                                   \
    for (int k = 0; k < (cc); ++k) {                                    \
      float2 lo = arr[k], hi = arr[k + (cc)];                           \
      float sx = up ? lo.x : hi.x, sy = up ? lo.y : hi.y;               \
      float rx = __shfl_xor(sx, (mm), 64);                              \
      float ry = __shfl_xor(sy, (mm), 64);                              \
      arr[k].x = (up ? hi.x : lo.x) + rx;                               \
      arr[k].y = (up ? hi.y : lo.y) + ry;                               \
    }                                                                   \
  }
// after RFULL, all 4 lanes of group (lane>>2) hold in arr[0] the FULL
// 64-lane sum for b=(lane>>2)&15 (.x = even row, .y = odd row)
#define RFULL(arr)                                                      \
  RSTEP2(arr, 32, 8)                                                    \
  RSTEP2(arr, 16, 4)                                                    \
  RSTEP2(arr, 8, 2)                                                     \
  RSTEP2(arr, 4, 1)                                                     \
  arr[0].x += __shfl_xor(arr[0].x, 2, 64);                              \
  arr[0].y += __shfl_xor(arr[0].y, 2, 64);                              \
  arr[0].x += __shfl_xor(arr[0].x, 1, 64);                              \
  arr[0].y += __shfl_xor(arr[0].y, 1, 64);

// ---- K1 (persistent): pd[q][b][n] = c1*dot_q(x_b,img_n) - c2*isq_q(n) ----
// grid (192, 4) x 256 thr (4 waves). Block p, quarter q: stages x[:,q]
// once, then handles n-groups p, p+192, p+384, p+576 (<625). Wave owns
// rows g*16+wave*4 .. +3, 3 chunks of 256 floats each. Prefetch of the
// NEXT group's chunk 0 is issued at the top of chunk 2, so the shuffle
// reduce-tail and pd write run with 4 KB/wave of image loads in flight.
__global__ __launch_bounds__(256, 3) void k1_partial(
    const float* __restrict__ x, const float* __restrict__ images,
    const float* __restrict__ svalp, float* __restrict__ pd)
{
  __shared__ float xs[BB * DQ];                // 48 KB, single buffer
  const int t = threadIdx.x;
  const int lane = t & 63;
  const int wave = t >> 6;
  const int q = blockIdx.y;
  const int qb = q * DQ;
  const int p = blockIdx.x;
  const int dl = lane << 2;

  // stage x[:, qb..qb+767] once: wave w stages b = 4w..4w+3, 3 chunks each.
  // LDS dest = wave-uniform base + lane*16 (DMA constraint, m104/m108).
#pragma unroll
  for (int i = 0; i < 4; ++i) {
    const int b = wave * 4 + i;
#pragma unroll
    for (int cc = 0; cc < 3; ++cc) {
      __builtin_amdgcn_global_load_lds(
          (gas_t)(x + b * DD + qb + cc * 256 + dl),
          (las_t)(&xs[b * DQ + cc * 256]), 16, 0, 0);
    }
  }

  const float sval = *svalp;
  const float at = sqrtf(1.f - sval);
  const float k1c = at / sval;                    // at / bt2
  const float k2c = (1.f - sval) / (2.f * sval);  // at^2 / (2*bt2)

  const float* __restrict__ ibase = images + qb;

  // prefetch chunk 0 of the FIRST group; rides in front of barrier drain
  const float* r0 = ibase + (size_t)((p * 4 + wave) * 4) * DD;
  const float* r1 = r0 + DD;
  const float* r2 = r1 + DD;
  const float* r3 = r2 + DD;
  float4 c0 = ldnt4(r0 + dl);
  float4 c1 = ldnt4(r1 + dl);
  float4 c2 = ldnt4(r2 + dl);
  float4 c3 = ldnt4(r3 + dl);

  __syncthreads();                             // drains staging DMA (once)

#pragma unroll 1
  for (int bx = p; bx < NGRP; bx += PBX) {
    const int nbx = bx + PBX;
    const int nbxc = (nbx < NGRP) ? nbx : bx;  // clamp: last-group prefetch
    const float* s0 = ibase + (size_t)((nbxc * 4 + wave) * 4) * DD;

    float2 acc0[BB], acc1[BB];                 // pair0 = rows 0/1, pair1 = 2/3
    float2 isq0 = make_float2(0.f, 0.f), isq1 = make_float2(0.f, 0.f);
#pragma unroll
    for (int b = 0; b < BB; ++b) {
      acc0[b] = make_float2(0.f, 0.f);
      acc1[b] = make_float2(0.f, 0.f);
    }

#pragma unroll 1
    for (int c = 0; c < 3; ++c) {
      float4 A0 = c0, A1 = c1, A2 = c2, A3 = c3;
      if (c < 2) {                             // roll image prefetch in-group
        const int dn = (c + 1) * 256 + dl;
        c0 = ldnt4(r0 + dn);
        c1 = ldnt4(r1 + dn);
        c2 = ldnt4(r2 + dn);
        c3 = ldnt4(r3 + dn);
      } else {                                 // roll into NEXT group chunk 0
        c0 = ldnt4(s0 + dl);
        c1 = ldnt4(s0 + DD + dl);
        c2 = ldnt4(s0 + 2 * DD + dl);
        c3 = ldnt4(s0 + 3 * DD + dl);
      }

      isq0.x += A0.x * A0.x + A0.y * A0.y + A0.z * A0.z + A0.w * A0.w;
      isq0.y += A1.x * A1.x + A1.y * A1.y + A1.z * A1.z + A1.w * A1.w;
      isq1.x += A2.x * A2.x + A2.y * A2.y + A2.z * A2.z + A2.w * A2.w;
      isq1.y += A3.x * A3.x + A3.y * A3.y + A3.z * A3.z + A3.w * A3.w;

      const float* xb = &xs[c * 256 + dl];
#pragma unroll
      for (int b = 0; b < BB; ++b) {
        float4 xv = *(const float4*)&xb[b * DQ];  // ds_read_b128, conflict-free
        acc0[b].x += A0.x * xv.x + A0.y * xv.y + A0.z * xv.z + A0.w * xv.w;
        acc0[b].y += A1.x * xv.x + A1.y * xv.y + A1.z * xv.z + A1.w * xv.w;
        acc1[b].x += A2.x * xv.x + A2.y * xv.y + A2.z * xv.z + A2.w * xv.w;
        acc1[b].y += A3.x * xv.x + A3.y * xv.y + A3.z * xv.z + A3.w * xv.w;
      }
    }

    // one reduction per wave per group (verified R6/R8/R9 sequence);
    // next group's chunk-0 loads are in flight underneath this tail.
    RFULL(acc0)
    RFULL(acc1)
#pragma unroll
    for (int m = 32; m >= 1; m >>= 1) {
      isq0.x += __shfl_xor(isq0.x, m, 64);
      isq0.y += __shfl_xor(isq0.y, m, 64);
      isq1.x += __shfl_xor(isq1.x, m, 64);
      isq1.y += __shfl_xor(isq1.y, m, 64);
    }

    const int r = lane & 1;
    const int bb = (lane >> 2) & 15;
    if ((lane & 2) == 0) {
      const int n0w = bx * 16 + wave * 4;
      float d0 = r ? acc0[0].y : acc0[0].x;
      float s0v = r ? isq0.y : isq0.x;
      pd[((size_t)q * BB + bb) * NN + (n0w + r)] = k1c * d0 - k2c * s0v;
      float d1 = r ? acc1[0].y : acc1[0].x;
      float s1v = r ? isq1.y : isq1.x;
      pd[((size_t)q * BB + bb) * NN + (n0w + 2 + r)] = k1c * d1 - k2c * s1v;
    }

    r0 = s0; r1 = s0 + DD; r2 = s0 + 2 * DD; r3 = s0 + 3 * DD;
  }
}

// ---- K2 (merged): args = sum_q pd -> stats + select (LDS) + sparse mix ----
// 16 blocks x 1024 thr; thread t owns n = t, t+1024, ... (<=10 values).
// Selection kept in LDS (sidx/swv); mix + final affine fused in-block.
__global__ __launch_bounds__(1024) void k2_mix(
    const float* __restrict__ pd, const float* __restrict__ images,
    const float* __restrict__ x, const float* __restrict__ svalp,
    float* __restrict__ out)
{
  __shared__ float red[16];
  __shared__ float mshared, lshared;
  __shared__ int scnt;
  __shared__ int sidx[CAP];
  __shared__ float swv[CAP];
  const int b = blockIdx.x;
  const int t = threadIdx.x;
  const int lane = t & 63, wave = t >> 6;
  if (t == 0) scnt = 0;

  float a[10];
#pragma unroll
  for (int i = 0; i < 10; ++i) {
    int n = t + (i << 10);
    if (n < NN) {
      a[i] = (pd[((size_t)0 * BB + b) * NN + n] +
              pd[((size_t)1 * BB + b) * NN + n]) +
             (pd[((size_t)2 * BB + b) * NN + n] +
              pd[((size_t)3 * BB + b) * NN + n]);
    } else {
      a[i] = -INFINITY;
    }
  }

  float mx = -INFINITY;
#pragma unroll
  for (int i = 0; i < 10; ++i) mx = fmaxf(mx, a[i]);
#pragma unroll
  for (int m = 32; m >= 1; m >>= 1) mx = fmaxf(mx, __shfl_xor(mx, m, 64));
  if (lane == 0) red[wave] = mx;
  __syncthreads();
  if (wave == 0) {
    float v = (lane < 16) ? red[lane] : -INFINITY;
#pragma unroll
    for (int m = 8; m >= 1; m >>= 1) v = fmaxf(v, __shfl_xor(v, m, 64));
    if (lane == 0) mshared = v;
  }
  __syncthreads();
  mx = mshared;

  float s = 0.f;
#pragma unroll
  for (int i = 0; i < 10; ++i) s += __expf(a[i] - mx);  // exp(-inf)=0
#pragma unroll
  for (int m = 32; m >= 1; m >>= 1) s += __shfl_xor(s, m, 64);
  if (lane == 0) red[wave] = s;
  __syncthreads();
  if (wave == 0) {
    float v = (lane < 16) ? red[lane] : 0.f;
#pragma unroll
    for (int m = 8; m >= 1; m >>= 1) v += __shfl_xor(v, m, 64);
    if (lane == 0) lshared = v;
  }
  __syncthreads();
  const float invl = 1.f / lshared;

#pragma unroll
  for (int i = 0; i < 10; ++i) {
    if (a[i] > mx - SEL_CUT) {               // ~1-5 hits per row
      int k = atomicAdd(&scnt, 1);
      if (k < CAP) {
        sidx[k] = t + (i << 10);
        swv[k] = __expf(a[i] - mx) * invl;
      }
    }
  }
  __syncthreads();
  int c = scnt;
  if (c > CAP) c = CAP;

  // sparse mix + fused final affine: threads 0..767 cover D via float4
  const float sval = *svalp;
  const float at = sqrtf(1.f - sval);
  const float inv_bt2 = 1.f / sval;
  if (t < 768) {
    const int d0 = t << 2;
    float4 acc = make_float4(0.f, 0.f, 0.f, 0.f);
    for (int j = 0; j < c; ++j) {
      const int n = sidx[j];
      const float w = swv[j];
      float4 im = *(const float4*)&images[(size_t)n * DD + d0];
      acc.x += w * im.x; acc.y += w * im.y;
      acc.z += w * im.z; acc.w += w * im.w;
    }
    float4 xv = *(const float4*)&x[b * DD + d0];
    float4 o;
    o.x = (at * acc.x - xv.x) * inv_bt2;
    o.y = (at * acc.y - xv.y) * inv_bt2;
    o.z = (at * acc.z - xv.z) * inv_bt2;
    o.w = (at * acc.w - xv.w) * inv_bt2;
    *(float4*)&out[b * DD + d0] = o;
  }
}

extern "C" void kernel_launch(void* const* d_in, const int* in_sizes, int n_in,
                              void* d_out, int out_size, void* d_ws, size_t ws_size,
                              hipStream_t stream) {
  const float* x      = (const float*)d_in[0];
  const float* images = (const float*)d_in[1];
  const float* sval   = (const float*)d_in[2];
  float* out = (float*)d_out;

  // ws layout (floats): pd[4*16*10000] -> 2.56 MB (selection now in LDS)
  float* pd = (float*)d_ws;

  hipLaunchKernelGGL(k1_partial, dim3(PBX, 4), dim3(256), 0, stream,
                     x, images, sval, pd);
  hipLaunchKernelGGL(k2_mix, dim3(16), dim3(1024), 0, stream,
                     pd, images, x, sval, out);
}